// Round 3
// baseline (213.013 us; speedup 1.0000x reference)
//
#include <hip/hip_runtime.h>

typedef _Float16 half_t;
typedef _Float16 half8  __attribute__((ext_vector_type(8)));
typedef _Float16 half4v __attribute__((ext_vector_type(4)));
typedef float    f32x16 __attribute__((ext_vector_type(16)));
typedef float    f32x4  __attribute__((ext_vector_type(4)));

#define DEVI static __device__ __forceinline__

constexpr int B_  = 16384;
constexpr int T_  = 28;
constexpr int IN_ = 28;
constexpr int H_  = 128;
constexpr int C_  = 11;
constexpr int BT  = 64;    // batch rows per block (grid = 256 blocks = 1/CU)
constexpr int NT  = 512;   // threads: 8 waves = 4 m-tiles x 2 n-tiles -> 2 waves/SIMD
constexpr int HSTR = 136;  // LDS stride (halves) for h: 272B rows, 16B-aligned
constexpr int XSTR = 40;   // LDS stride (halves) for x tile (K padded 28->32)

struct SMem {
  alignas(16) half_t h[3][BT * HSTR];  // per-layer recurrent state [b][n]
  alignas(16) half_t xin[BT * XSTR];   // staged x_t tile [b][k]; cols 28..31 stay 0
  alignas(16) float  bias[3][H_];      // combined bih+bhh per layer
};

DEVI f32x16 mfma(half8 a, half8 b, f32x16 c) {
  return __builtin_amdgcn_mfma_f32_32x32x16_f16(a, b, c, 0, 0, 0);
}

// A-fragments for one 32-row m-tile of a 128x128 row-major fp32 weight matrix.
// A layout (32x32x16 f16): lane holds A[m=lane&31][k=(lane>>5)*8+j], j=0..7.
DEVI void loadw(half8 d[8], const float* __restrict__ w, int m, int hf) {
  const float* p = w + m * H_ + hf * 8;
#pragma unroll
  for (int kc = 0; kc < 8; ++kc) {
    half8 f;
#pragma unroll
    for (int j = 0; j < 8; ++j) f[j] = (half_t)p[kc * 16 + j];
    d[kc] = f;
  }
}

// acc(e,o) = Wih . in^T + Whh . hprev^T for one (m-tile, n-tile).
// Even/odd kc split keeps two independent MFMA dependency chains.
template <int KIN, int ISTR>
DEVI void mmstep(const half_t* __restrict__ inb, const half_t* __restrict__ hp,
                 const half8* awi, const half8* awh,
                 f32x16& e, f32x16& o, int brow, int hf) {
  f32x16 ae = {};
  f32x16 ao = {};
#pragma unroll
  for (int kc = 0; kc < KIN; ++kc) {
    half8 b = *(const half8*)&inb[brow * ISTR + kc * 16 + hf * 8];
    if (kc & 1) ao = mfma(awi[kc], b, ao);
    else        ae = mfma(awi[kc], b, ae);
  }
#pragma unroll
  for (int kc = 0; kc < 8; ++kc) {
    half8 b = *(const half8*)&hp[brow * HSTR + kc * 16 + hf * 8];
    if (kc & 1) ao = mfma(awh[kc], b, ao);
    else        ae = mfma(awh[kc], b, ae);
  }
  e = ae;
  o = ao;
}

// h = relu(e + o + bias) -> LDS.  C/D layout (HW-verified m74/m101):
// col = lane&31 (batch), row = (reg&3) + 8*(reg>>2) + 4*(lane>>5).
DEVI void epi(half_t* __restrict__ hout, const float* __restrict__ bl,
              f32x16 e, f32x16 o, int mt, int brow, int hf) {
#pragma unroll
  for (int rq = 0; rq < 4; ++rq) {
    const int n0 = mt * 32 + rq * 8 + hf * 4;
    const f32x4 b4 = *(const f32x4*)&bl[n0];   // same-addr broadcast: free
    half4v h4;
#pragma unroll
    for (int ri = 0; ri < 4; ++ri)
      h4[ri] = (half_t)fmaxf(e[rq * 4 + ri] + o[rq * 4 + ri] + b4[ri], 0.0f);
    *(half4v*)&hout[brow * HSTR + n0] = h4;
  }
}

__global__ __launch_bounds__(NT, 2)
void rnn_fused(const float* __restrict__ x,
               const float* __restrict__ wih0, const float* __restrict__ whh0,
               const float* __restrict__ bih0, const float* __restrict__ bhh0,
               const float* __restrict__ wih1, const float* __restrict__ whh1,
               const float* __restrict__ bih1, const float* __restrict__ bhh1,
               const float* __restrict__ wih2, const float* __restrict__ whh2,
               const float* __restrict__ bih2, const float* __restrict__ bhh2,
               const float* __restrict__ fcw, const float* __restrict__ fcb,
               float* __restrict__ out)
{
  __shared__ SMem sm;
  const int tid  = threadIdx.x;
  const int b0   = blockIdx.x * BT;
  const int lane = tid & 63;
  const int wid  = tid >> 6;
  const int mt   = wid & 3;        // m-tile: hidden rows [mt*32, +32)
  const int nt   = wid >> 2;       // n-tile: batch cols [nt*32, +32)
  const int l31  = lane & 31;
  const int hf   = lane >> 5;
  const int m    = mt * 32 + l31;
  const int brow = nt * 32 + l31;  // this lane's batch row in LDS tiles

  // ---- register-resident weights for ALL layers (held across all 28 steps) ----
  half8 ah0[8], ai1[8], ah1[8], ai2[8], ah2[8], ai0[2];
  loadw(ah0, whh0, m, hf);
  loadw(ai1, wih1, m, hf);
  loadw(ah1, whh1, m, hf);
  loadw(ai2, wih2, m, hf);
  loadw(ah2, whh2, m, hf);
#pragma unroll
  for (int kc = 0; kc < 2; ++kc) {   // wih0: K=28 padded to 32
    half8 f;
#pragma unroll
    for (int j = 0; j < 8; ++j) {
      const int k = kc * 16 + hf * 8 + j;
      f[j] = (k < IN_) ? (half_t)wih0[m * IN_ + k] : (half_t)0.0f;
    }
    ai0[kc] = f;
  }

  // ---- zero h[0..2] + xin; stage combined biases ----
  for (int i = tid; i < (3 * BT * HSTR + BT * XSTR) / 2; i += NT)
    ((unsigned int*)sm.h)[i] = 0u;
  if (tid < H_) {
    sm.bias[0][tid] = bih0[tid] + bhh0[tid];
    sm.bias[1][tid] = bih1[tid] + bhh1[tid];
    sm.bias[2][tid] = bih2[tid] + bhh2[tid];
  }
  __syncthreads();

  // ---- x prefetch: thread covers row=tid>>3, 4 floats at col (tid&7)*4 ----
  const int prow = tid >> 3, pc0 = (tid & 7) * 4;
  const float* xrow = x + (size_t)(b0 + prow) * T_ * IN_ + pc0;
  float xr[4];
#pragma unroll
  for (int j = 0; j < 4; ++j) xr[j] = (pc0 + j < IN_) ? xrow[j] : 0.0f;   // t = 0

  f32x16 e, o;
  for (int t = 0; t < T_; ++t) {
#pragma unroll
    for (int j = 0; j < 4; ++j)
      if (pc0 + j < IN_) sm.xin[prow * XSTR + pc0 + j] = (half_t)xr[j];
    __syncthreads();                                   // xin ready
    mmstep<2, XSTR>(sm.xin, sm.h[0], ai0, ah0, e, o, brow, hf);
    if (t + 1 < T_) {                                  // prefetch x_{t+1}
      const float* xn = xrow + (t + 1) * IN_;
#pragma unroll
      for (int j = 0; j < 4; ++j) xr[j] = (pc0 + j < IN_) ? xn[j] : 0.0f;
    }
    __syncthreads();                                   // all reads of h0_old done
    epi(sm.h[0], sm.bias[0], e, o, mt, brow, hf);
    __syncthreads();                                   // h0_new visible
    mmstep<8, HSTR>(sm.h[0], sm.h[1], ai1, ah1, e, o, brow, hf);
    __syncthreads();
    epi(sm.h[1], sm.bias[1], e, o, mt, brow, hf);
    __syncthreads();
    mmstep<8, HSTR>(sm.h[1], sm.h[2], ai2, ah2, e, o, brow, hf);
    __syncthreads();
    epi(sm.h[2], sm.bias[2], e, o, mt, brow, hf);
    // next use of h2 (mm L2 at t+1) is 5 syncs away — no trailing sync needed
  }
  __syncthreads();   // h2 final visible for FC

  // ---- FC head: out[b][c] = h2_last[b] . fcw[c] + fcb[c] ----
  const int row = tid >> 3, q = tid & 7;
  for (int c = q; c < C_; c += 8) {
    float s = fcb[c];
    const float* wp = fcw + c * H_;
#pragma unroll
    for (int k = 0; k < H_; k += 8) {
      const half8 hv = *(const half8*)&sm.h[2][row * HSTR + k];
#pragma unroll
      for (int j = 0; j < 8; ++j) s += (float)hv[j] * wp[k + j];
    }
    out[(size_t)(b0 + row) * C_ + c] = s;
  }
}

extern "C" void kernel_launch(void* const* d_in, const int* in_sizes, int n_in,
                              void* d_out, int out_size, void* d_ws, size_t ws_size,
                              hipStream_t stream)
{
  const float* x    = (const float*)d_in[0];
  const float* wih0 = (const float*)d_in[1];
  const float* whh0 = (const float*)d_in[2];
  const float* bih0 = (const float*)d_in[3];
  const float* bhh0 = (const float*)d_in[4];
  const float* wih1 = (const float*)d_in[5];
  const float* whh1 = (const float*)d_in[6];
  const float* bih1 = (const float*)d_in[7];
  const float* bhh1 = (const float*)d_in[8];
  const float* wih2 = (const float*)d_in[9];
  const float* whh2 = (const float*)d_in[10];
  const float* bih2 = (const float*)d_in[11];
  const float* bhh2 = (const float*)d_in[12];
  const float* fcw  = (const float*)d_in[13];
  const float* fcb  = (const float*)d_in[14];
  float* out = (float*)d_out;

  rnn_fused<<<B_ / BT, NT, 0, stream>>>(x,
      wih0, whh0, bih0, bhh0,
      wih1, whh1, bih1, bhh1,
      wih2, whh2, bih2, bhh2,
      fcw, fcb, out);
}

// Round 4
// 209.908 us; speedup vs baseline: 1.0148x; 1.0148x over previous
//
#include <hip/hip_runtime.h>

typedef _Float16 half_t;
typedef _Float16 half8  __attribute__((ext_vector_type(8)));
typedef _Float16 half4v __attribute__((ext_vector_type(4)));
typedef float    f32x16 __attribute__((ext_vector_type(16)));
typedef float    f32x4  __attribute__((ext_vector_type(4)));
typedef float    f32x4a __attribute__((ext_vector_type(4)));

#define DEVI static __device__ __forceinline__

constexpr int B_  = 16384;
constexpr int T_  = 28;
constexpr int IN_ = 28;
constexpr int H_  = 128;
constexpr int C_  = 11;
constexpr int BT  = 32;    // batch rows per block; grid = 512 = 2 blocks/CU
constexpr int NT  = 256;   // 4 waves = 4 m-tiles x 1 n-tile
constexpr int HSTR = 136;  // LDS stride (halves): 272B rows, 16B-aligned, 2-way banks
constexpr int XSTR = 40;   // LDS stride (halves) for x tile: 80B rows, 16B-aligned

struct SMem {
  alignas(16) half_t h[3][2][BT * HSTR];  // [layer][buf][b*HSTR+n], double-buffered
  alignas(16) half_t xin[2][BT * XSTR];   // staged x_t tile [b][k]; cols 28.. stay 0
  alignas(16) float  bias[3][H_];         // combined bih+bhh
};

DEVI f32x16 mfma(half8 a, half8 b, f32x16 c) {
  return __builtin_amdgcn_mfma_f32_32x32x16_f16(a, b, c, 0, 0, 0);
}

// A-fragments, one 32-row m-tile of a 128x128 row-major fp32 matrix.
// A layout (32x32x16 f16): lane holds A[m=lane&31][k=(lane>>5)*8+j], j=0..7.
DEVI void loadw(half8 d[8], const float* __restrict__ w, int m, int hf) {
  const float* p = w + m * H_ + hf * 8;
#pragma unroll
  for (int kc = 0; kc < 8; ++kc) {
    half8 f;
#pragma unroll
    for (int j = 0; j < 8; ++j) f[j] = (half_t)p[kc * 16 + j];
    d[kc] = f;
  }
}

// acc(e,o) = Wih . in^T + Whh . hprev^T for this wave's m-tile, full 32-batch n-tile.
template <int KIN, int ISTR>
DEVI void mmstep(const half_t* __restrict__ inb, const half_t* __restrict__ hp,
                 const half8* awi, const half8* awh,
                 f32x16& e, f32x16& o, int l31, int hf) {
  f32x16 ae = {};
  f32x16 ao = {};
#pragma unroll
  for (int kc = 0; kc < KIN; ++kc) {
    half8 b = *(const half8*)&inb[l31 * ISTR + kc * 16 + hf * 8];
    if (kc & 1) ao = mfma(awi[kc], b, ao);
    else        ae = mfma(awi[kc], b, ae);
  }
#pragma unroll
  for (int kc = 0; kc < 8; ++kc) {
    half8 b = *(const half8*)&hp[l31 * HSTR + kc * 16 + hf * 8];
    if (kc & 1) ao = mfma(awh[kc], b, ao);
    else        ae = mfma(awh[kc], b, ae);
  }
  e = ae;
  o = ao;
}

// h = relu(e + o + bias) -> hout.  C/D layout (HW-verified m74/m101):
// col = lane&31 (batch), row = (reg&3) + 8*(reg>>2) + 4*(lane>>5).
DEVI void epi(half_t* __restrict__ hout, const float* __restrict__ bl,
              f32x16 e, f32x16 o, int mt, int l31, int hf) {
#pragma unroll
  for (int rq = 0; rq < 4; ++rq) {
    const int n0 = mt * 32 + rq * 8 + hf * 4;
    const f32x4 b4 = *(const f32x4*)&bl[n0];   // 2-addr broadcast: cheap
    half4v h4;
#pragma unroll
    for (int ri = 0; ri < 4; ++ri)
      h4[ri] = (half_t)fmaxf(e[rq * 4 + ri] + o[rq * 4 + ri] + b4[ri], 0.0f);
    *(half4v*)&hout[l31 * HSTR + n0] = h4;
  }
}

// Stage x[:, t, :] (32 rows x 28 cols fp32) -> xin buf as fp16. ch<7 covers cols 0..27.
DEVI void stage_x(half_t* __restrict__ xb, const float* __restrict__ x,
                  int b0, int t, int tid) {
  const int row = tid >> 3, ch = tid & 7;
  if (ch < 7) {
    const f32x4a v = *(const f32x4a*)(x + (size_t)(b0 + row) * (T_ * IN_) +
                                      (size_t)t * IN_ + ch * 4);
    half4v h4;
#pragma unroll
    for (int j = 0; j < 4; ++j) h4[j] = (half_t)v[j];
    *(half4v*)&xb[row * XSTR + ch * 4] = h4;
  }
}

__global__ __launch_bounds__(NT) __attribute__((amdgpu_waves_per_eu(2, 2)))
void rnn_fused(const float* __restrict__ x,
               const float* __restrict__ wih0, const float* __restrict__ whh0,
               const float* __restrict__ bih0, const float* __restrict__ bhh0,
               const float* __restrict__ wih1, const float* __restrict__ whh1,
               const float* __restrict__ bih1, const float* __restrict__ bhh1,
               const float* __restrict__ wih2, const float* __restrict__ whh2,
               const float* __restrict__ bih2, const float* __restrict__ bhh2,
               const float* __restrict__ fcw, const float* __restrict__ fcb,
               float* __restrict__ out)
{
  __shared__ SMem sm;
  const int tid  = threadIdx.x;
  const int b0   = blockIdx.x * BT;
  const int lane = tid & 63;
  const int mt   = tid >> 6;       // m-tile: hidden rows [mt*32, +32)
  const int l31  = lane & 31;      // batch row within the 32-row n-tile
  const int hf   = lane >> 5;
  const int m    = mt * 32 + l31;

  // ---- register-resident weights for ALL layers (held across all 28 steps) ----
  half8 ah0[8], ai1[8], ah1[8], ai2[8], ah2[8], ai0[2];
  loadw(ah0, whh0, m, hf);
  loadw(ai1, wih1, m, hf);
  loadw(ah1, whh1, m, hf);
  loadw(ai2, wih2, m, hf);
  loadw(ah2, whh2, m, hf);
#pragma unroll
  for (int kc = 0; kc < 2; ++kc) {   // wih0: K=28 padded to 32 with zeros
    half8 f;
#pragma unroll
    for (int j = 0; j < 8; ++j) {
      const int k = kc * 16 + hf * 8 + j;
      f[j] = (k < IN_) ? (half_t)wih0[m * IN_ + k] : (half_t)0.0f;
    }
    ai0[kc] = f;
  }

  // ---- zero h[*][0] and both xin bufs (pad cols must be 0, not poison) ----
#pragma unroll
  for (int l = 0; l < 3; ++l)
    for (int i = tid; i < BT * HSTR / 2; i += NT)
      ((unsigned int*)sm.h[l][0])[i] = 0u;
  for (int i = tid; i < 2 * BT * XSTR / 2; i += NT)
    ((unsigned int*)sm.xin)[i] = 0u;
  if (tid < H_) {
    sm.bias[0][tid] = bih0[tid] + bhh0[tid];
    sm.bias[1][tid] = bih1[tid] + bhh1[tid];
    sm.bias[2][tid] = bih2[tid] + bhh2[tid];
  }
  __syncthreads();
  stage_x(sm.xin[0], x, b0, 0, tid);
  __syncthreads();

  f32x16 e, o;
  for (int t = 0; t < T_; ++t) {
    const int p = t & 1, np = p ^ 1;
    // L0: reads xin[p], h0[p]; writes h0[np] — no sync needed before epi (dbuf)
    mmstep<2, XSTR>(sm.xin[p], sm.h[0][p], ai0, ah0, e, o, l31, hf);
    if (t + 1 < T_) stage_x(sm.xin[np], x, b0, t + 1, tid);  // overlaps epi/mm1
    epi(sm.h[0][np], sm.bias[0], e, o, mt, l31, hf);
    __syncthreads();                       // h0[np] visible
    mmstep<8, HSTR>(sm.h[0][np], sm.h[1][p], ai1, ah1, e, o, l31, hf);
    epi(sm.h[1][np], sm.bias[1], e, o, mt, l31, hf);
    __syncthreads();                       // h1[np] visible
    mmstep<8, HSTR>(sm.h[1][np], sm.h[2][p], ai2, ah2, e, o, l31, hf);
    epi(sm.h[2][np], sm.bias[2], e, o, mt, l31, hf);
    __syncthreads();                       // h2[np] + xin[np] visible for t+1
  }
  // after t=27 (p=1): final h2 in buf 0

  // ---- FC head: out[b][c] = h2_last[b] . fcw[c] + fcb[c] ----
  const int row = tid >> 3, q = tid & 7;
  for (int c = q; c < C_; c += 8) {
    float s = fcb[c];
    const float* wp = fcw + c * H_;
#pragma unroll
    for (int k = 0; k < H_; k += 8) {
      const half8 hv = *(const half8*)&sm.h[2][0][row * HSTR + k];
#pragma unroll
      for (int j = 0; j < 8; ++j) s += (float)hv[j] * wp[k + j];
    }
    out[(size_t)(b0 + row) * C_ + c] = s;
  }
}

extern "C" void kernel_launch(void* const* d_in, const int* in_sizes, int n_in,
                              void* d_out, int out_size, void* d_ws, size_t ws_size,
                              hipStream_t stream)
{
  const float* x    = (const float*)d_in[0];
  const float* wih0 = (const float*)d_in[1];
  const float* whh0 = (const float*)d_in[2];
  const float* bih0 = (const float*)d_in[3];
  const float* bhh0 = (const float*)d_in[4];
  const float* wih1 = (const float*)d_in[5];
  const float* whh1 = (const float*)d_in[6];
  const float* bih1 = (const float*)d_in[7];
  const float* bhh1 = (const float*)d_in[8];
  const float* wih2 = (const float*)d_in[9];
  const float* whh2 = (const float*)d_in[10];
  const float* bih2 = (const float*)d_in[11];
  const float* bhh2 = (const float*)d_in[12];
  const float* fcw  = (const float*)d_in[13];
  const float* fcb  = (const float*)d_in[14];
  float* out = (float*)d_out;

  rnn_fused<<<B_ / BT, NT, 0, stream>>>(x,
      wih0, whh0, bih0, bhh0,
      wih1, whh1, bih1, bhh1,
      wih2, whh2, bih2, bhh2,
      fcw, fcb, out);
}